// Round 1
// baseline (399.169 us; speedup 1.0000x reference)
//
#include <hip/hip_runtime.h>
#include <hip/hip_bf16.h>

// Problem constants
// B=2, M=256, N=256, K=8, P=Q=Pp=Qp=512, D=Dp=64, R=128, TEMP=8

// ---------------------------------------------------------------------------
// Generic tiled GEMM: per batch z: C[i,j] = sum_kk A(i,kk)*B(kk,j) (opt row scale)
// Tile 64x64, 256 threads, 4x4 micro-tile per thread, K-chunks of 16.
// A(i,kk) = A[i*lda + kk]  (TA=0)  or  A[kk*lda + i]  (TA=1)
// B(kk,j) = B[kk*ldb + j]  (TB=0)  or  B[j*ldb + kk]  (TB=1)
// batch decomposition: zb -> b = zb/ksplit, k = zb%ksplit
// ---------------------------------------------------------------------------
template<int TA, int TB, int USE_SCALE>
__global__ __launch_bounds__(256)
void gemm64(const float* __restrict__ Abase, const float* __restrict__ Bbase,
            float* __restrict__ Cbase,
            int lda, int ldb, int ldc, int Kdim,
            long sA_b, long sA_k, long sB_b, long sB_k, long sC_b, long sC_k,
            int ksplit, const float* __restrict__ scaleBase, long sScale)
{
    const int zb = blockIdx.z;
    const int b  = zb / ksplit;
    const int k  = zb % ksplit;
    const float* A = Abase + b * sA_b + k * sA_k;
    const float* B = Bbase + b * sB_b + k * sB_k;
    float*       C = Cbase + b * sC_b + k * sC_k;
    const int i0 = blockIdx.y * 64;
    const int j0 = blockIdx.x * 64;

    __shared__ float As[16][65];
    __shared__ float Bs[16][65];

    const int tid = threadIdx.x;
    const int tx = tid % 16;  // -> i micro
    const int ty = tid / 16;  // -> j micro

    float acc[4][4] = {};

    for (int k0 = 0; k0 < Kdim; k0 += 16) {
        if (!TA) {
            const int kk = tid % 16;
            const int ib = tid / 16;
            #pragma unroll
            for (int rep = 0; rep < 4; rep++) {
                const int i = ib + rep * 16;
                As[kk][i] = A[(long)(i0 + i) * lda + (k0 + kk)];
            }
        } else {
            const int i  = tid % 64;
            const int kb = tid / 64;
            #pragma unroll
            for (int rep = 0; rep < 4; rep++) {
                const int kk = kb + rep * 4;
                As[kk][i] = A[(long)(k0 + kk) * lda + (i0 + i)];
            }
        }
        if (!TB) {
            const int j  = tid % 64;
            const int kb = tid / 64;
            #pragma unroll
            for (int rep = 0; rep < 4; rep++) {
                const int kk = kb + rep * 4;
                Bs[kk][j] = B[(long)(k0 + kk) * ldb + (j0 + j)];
            }
        } else {
            const int kk = tid % 16;
            const int jb = tid / 16;
            #pragma unroll
            for (int rep = 0; rep < 4; rep++) {
                const int j = jb + rep * 16;
                Bs[kk][j] = B[(long)(j0 + j) * ldb + (k0 + kk)];
            }
        }
        __syncthreads();
        #pragma unroll
        for (int kk = 0; kk < 16; kk++) {
            float a[4], bb[4];
            #pragma unroll
            for (int ii = 0; ii < 4; ii++) a[ii] = As[kk][tx * 4 + ii];
            #pragma unroll
            for (int jj = 0; jj < 4; jj++) bb[jj] = Bs[kk][ty * 4 + jj];
            #pragma unroll
            for (int ii = 0; ii < 4; ii++)
                #pragma unroll
                for (int jj = 0; jj < 4; jj++)
                    acc[ii][jj] += a[ii] * bb[jj];
        }
        __syncthreads();
    }

    const float* srow = USE_SCALE ? (scaleBase + (long)zb * sScale) : nullptr;
    #pragma unroll
    for (int ii = 0; ii < 4; ii++) {
        const int i = i0 + tx * 4 + ii;
        const float sc = USE_SCALE ? (1.0f / srow[i]) : 1.0f;
        float4 v;
        v.x = acc[ii][0] * sc;
        v.y = acc[ii][1] * sc;
        v.z = acc[ii][2] * sc;
        v.w = acc[ii][3] * sc;
        *(float4*)(&C[(long)i * ldc + j0 + ty * 4]) = v;
    }
}

// ---------------------------------------------------------------------------
// Theta_y [K,Q,D] -> thyT [K*D, Q]   (B matrix for final GEMM, normal layout)
// ---------------------------------------------------------------------------
__global__ __launch_bounds__(256)
void transpose_thy(const float* __restrict__ thy, float* __restrict__ thyT)
{
    const int idx = blockIdx.x * 256 + threadIdx.x;  // over K*D*Q = 262144
    const int q  = idx & 511;
    const int kd = idx >> 9;
    const int k  = kd >> 6;
    const int d  = kd & 63;
    thyT[idx] = thy[((long)k * 512 + q) * 64 + d];
}

// ---------------------------------------------------------------------------
// Score kernel: r[b,k,m,n] = xt[b,k,m,:].yt[b,k,n,:]
//                          + sum_r z[b,m,n,r]*(wzy[b,k,m,r]+wzx[b,k,n,r])
// Block handles (b, 2 consecutive m), all k (8), all n (256).
// z is read exactly once from HBM.
// ---------------------------------------------------------------------------
#define SC_MT 2
__global__ __launch_bounds__(256)
void score_kernel(const float* __restrict__ z, const float* __restrict__ xt,
                  const float* __restrict__ yt, const float* __restrict__ wzy,
                  const float* __restrict__ wzx, float* __restrict__ rbuf)
{
    const int m0 = blockIdx.x * SC_MT;
    const int b  = blockIdx.y;

    __shared__ float wzy_s[SC_MT][8][128];  // 8 KB
    __shared__ float xt_s[SC_MT][8][64];    // 4 KB
    __shared__ float zs[SC_MT][8][128];     // 8 KB (8 n-rows per m)

    const int tid = threadIdx.x;

    for (int t = tid; t < SC_MT * 1024; t += 256) {
        const int mi = t >> 10, rem = t & 1023;
        const int k = rem >> 7, rr = rem & 127;
        wzy_s[mi][k][rr] = wzy[(((long)b * 8 + k) * 256 + m0 + mi) * 128 + rr];
    }
    for (int t = tid; t < SC_MT * 512; t += 256) {
        const int mi = t >> 9, rem = t & 511;
        const int k = rem >> 6, d = rem & 63;
        xt_s[mi][k][d] = xt[(((long)b * 8 + k) * 256 + m0 + mi) * 64 + d];
    }
    __syncthreads();

    const int kq = tid >> 5;  // 0..7 (head)
    const int j  = tid & 31;

    for (int n0 = 0; n0 < 256; n0 += 8) {
        __syncthreads();  // protect zs from previous iteration readers
        #pragma unroll
        for (int t = tid; t < SC_MT * 256; t += 256) {
            const int mi = t >> 8, rem = t & 255;
            ((float4*)zs)[mi * 256 + rem] =
                ((const float4*)(z + (((long)b * 256 + m0 + mi) * 256 + n0) * 128))[rem];
        }
        __syncthreads();

        for (int ni = 0; ni < 8; ni++) {
            const int n = n0 + ni;
            const float* wzxp = wzx + (((long)b * 8 + kq) * 256 + n) * 128;
            const float* ytp  = yt  + (((long)b * 8 + kq) * 256 + n) * 64;
            float wx[4], ytv[2];
            #pragma unroll
            for (int rr = 0; rr < 4; rr++) wx[rr] = wzxp[j + rr * 32];
            #pragma unroll
            for (int dd = 0; dd < 2; dd++) ytv[dd] = ytp[j + dd * 32];

            #pragma unroll
            for (int mi = 0; mi < SC_MT; mi++) {
                float s = 0.f;
                #pragma unroll
                for (int rr = 0; rr < 4; rr++) {
                    const int rI = j + rr * 32;
                    s += zs[mi][ni][rI] * (wzy_s[mi][kq][rI] + wx[rr]);
                }
                #pragma unroll
                for (int dd = 0; dd < 2; dd++)
                    s += xt_s[mi][kq][j + dd * 32] * ytv[dd];
                // reduce across the 32-lane group
                #pragma unroll
                for (int off = 16; off >= 1; off >>= 1)
                    s += __shfl_xor(s, off);
                if (j == 0)
                    rbuf[(((long)b * 8 + kq) * 256 + (m0 + mi)) * 256 + n] = s;
            }
        }
    }
}

// ---------------------------------------------------------------------------
// Column softmax over m (axis -2). Writes unnormalized e in place + column sums.
// grid (B*K, N/32); block 256 = 32 n x 8 m-groups.
// ---------------------------------------------------------------------------
__global__ __launch_bounds__(256)
void softmax_kernel(float* __restrict__ rbuf, float* __restrict__ ssum)
{
    const int bk = blockIdx.x;           // 0..15
    const int n0 = blockIdx.y * 32;
    const int tid = threadIdx.x;
    const int nn = tid % 32, mg = tid / 32;
    const int n = n0 + nn;
    float* col = rbuf + (long)bk * 65536 + n;

    __shared__ float red[8][33];
    __shared__ float colmax[32];

    float mx = -1e30f;
    for (int mm = 0; mm < 32; mm++)
        mx = fmaxf(mx, col[(mg * 32 + mm) * 256]);
    red[mg][nn] = mx;
    __syncthreads();
    if (mg == 0) {
        float m2 = red[0][nn];
        #pragma unroll
        for (int g = 1; g < 8; g++) m2 = fmaxf(m2, red[g][nn]);
        colmax[nn] = m2;
    }
    __syncthreads();
    const float cm = colmax[nn];
    const float sc = 0.18033688011112042f;  // (1/TEMP) * log2(e), TEMP = 8
    float s = 0.f;
    for (int mm = 0; mm < 32; mm++) {
        const long idx = (long)(mg * 32 + mm) * 256;
        const float e = exp2f((col[idx] - cm) * sc);
        col[idx] = e;
        s += e;
    }
    red[mg][nn] = s;
    __syncthreads();
    if (mg == 0) {
        float t = 0.f;
        #pragma unroll
        for (int g = 0; g < 8; g++) t += red[g][nn];
        ssum[bk * 256 + n] = t;
    }
}

// ---------------------------------------------------------------------------
extern "C" void kernel_launch(void* const* d_in, const int* in_sizes, int n_in,
                              void* d_out, int out_size, void* d_ws, size_t ws_size,
                              hipStream_t stream)
{
    const float* z       = (const float*)d_in[0];
    const float* y_q     = (const float*)d_in[1];
    const float* x_k     = (const float*)d_in[2];
    const float* Theta_x = (const float*)d_in[3];
    const float* Theta_y = (const float*)d_in[4];
    const float* Lam_x   = (const float*)d_in[5];
    const float* Lam_y   = (const float*)d_in[6];
    const float* Lam_zx  = (const float*)d_in[7];
    const float* Lam_zy  = (const float*)d_in[8];
    float* out = (float*)d_out;

    float* ws   = (float*)d_ws;
    float* xt   = ws;               // [B,K,256,64]  262144
    float* yt   = xt + 262144;      // [B,K,256,64]  262144
    float* xv   = yt + 262144;      // [B,K,256,64]  262144
    float* wzy  = xv + 262144;      // [B,K,256,128] 524288
    float* wzx  = wzy + 524288;     // [B,K,256,128] 524288
    float* rbuf = wzx + 524288;     // [B,K,256,256] 1048576
    float* ssum = rbuf + 1048576;   // [B*K,256]     4096
    float* o2   = ssum + 4096;      // [B,256,K*64]  262144
    float* thyT = o2 + 262144;      // [K*64, 512]   262144
    // total ~13.0 MiB of workspace

    // Theta_y permute (independent of everything else)
    transpose_thy<<<dim3(1024), 256, 0, stream>>>(Theta_y, thyT);

    // projections: out[b,k,i,d] = sum_p in[b,i,p] * W[k,p,d]
    dim3 gproj(1, 4, 16);
    gemm64<0,0,0><<<gproj, 256, 0, stream>>>(x_k, Lam_x, xt, 512, 64, 64, 512,
        131072L, 0L, 0L, 32768L, 131072L, 16384L, 8, nullptr, 0L);
    gemm64<0,0,0><<<gproj, 256, 0, stream>>>(y_q, Lam_y, yt, 512, 64, 64, 512,
        131072L, 0L, 0L, 32768L, 131072L, 16384L, 8, nullptr, 0L);
    gemm64<0,0,0><<<gproj, 256, 0, stream>>>(x_k, Theta_x, xv, 512, 64, 64, 512,
        131072L, 0L, 0L, 32768L, 131072L, 16384L, 8, nullptr, 0L);

    // wzy[b,k,m,r] = sum_d xt[b,k,m,d] * Lam_zy[k,r,d]   (B transposed)
    dim3 gwz(2, 4, 16);
    gemm64<0,1,0><<<gwz, 256, 0, stream>>>(xt, Lam_zy, wzy, 64, 64, 128, 64,
        131072L, 16384L, 0L, 8192L, 262144L, 32768L, 8, nullptr, 0L);
    gemm64<0,1,0><<<gwz, 256, 0, stream>>>(yt, Lam_zx, wzx, 64, 64, 128, 64,
        131072L, 16384L, 0L, 8192L, 262144L, 32768L, 8, nullptr, 0L);

    // scores
    score_kernel<<<dim3(128, 2), 256, 0, stream>>>(z, xt, yt, wzy, wzx, rbuf);

    // softmax over m
    softmax_kernel<<<dim3(16, 8), 256, 0, stream>>>(rbuf, ssum);

    // o2[b,n,k*64+d] = (1/ssum) * sum_m e[b,k,m,n] * xv[b,k,m,d]  (A transposed)
    dim3 go(1, 4, 16);
    gemm64<1,0,1><<<go, 256, 0, stream>>>(rbuf, xv, o2, 256, 64, 512, 256,
        524288L, 65536L, 131072L, 16384L, 131072L, 64L, 8, ssum, 256L);

    // y[b,n,q] = sum_kd o2[b,n,kd] * thyT[kd,q]
    dim3 gy(8, 4, 2);
    gemm64<0,0,0><<<gy, 256, 0, stream>>>(o2, thyT, out, 512, 512, 512, 512,
        131072L, 0L, 0L, 0L, 131072L, 0L, 1, nullptr, 0L);
}

// Round 2
// 131.081 us; speedup vs baseline: 3.0452x; 3.0452x over previous
//
#include <hip/hip_runtime.h>
#include <hip/hip_bf16.h>

// B=2, M=256, N=256, K=8, P=Q=Pp=Qp=512, D=Dp=64, R=128, TEMP=8
#define LOG2E_OVER_T 0.18033688011112042f  // log2(e)/8

// ---------------------------------------------------------------------------
// Shared GEMM body: 64x64 tile, 256 threads, 4x4 micro-tile, K-chunks of 16.
// Pad 68 -> aligned float4 LDS reads in the inner loop (2-way conflicts max).
// TA: 0 A[i*lda+kk], 1 A[kk*lda+i]
// TB: 0 B[kk*ldb+j], 1 B[j*ldb+kk], 2 Theta_y mode B[(kk/64)*32768 + j*64 + kk%64]
// ---------------------------------------------------------------------------
template<int TA, int TB, int USE_SCALE>
__device__ __forceinline__
void gemm_body(const float* __restrict__ A, const float* __restrict__ B,
               float* __restrict__ C, int lda, int ldb, int ldc, int Kdim,
               int i0, int j0, const float* __restrict__ srow)
{
    __shared__ __align__(16) float As[16][68];
    __shared__ __align__(16) float Bs[16][68];

    const int tid = threadIdx.x;
    const int tx = tid & 15, ty = tid >> 4;
    float acc[4][4] = {};

    for (int k0 = 0; k0 < Kdim; k0 += 16) {
        if (!TA) {
            const int kk = tid & 15, ib = tid >> 4;
            #pragma unroll
            for (int rep = 0; rep < 4; rep++)
                As[kk][ib + rep*16] = A[(long)(i0 + ib + rep*16)*lda + k0 + kk];
        } else {
            const int i = tid & 63, kb = tid >> 6;
            #pragma unroll
            for (int rep = 0; rep < 4; rep++)
                As[kb + rep*4][i] = A[(long)(k0 + kb + rep*4)*lda + i0 + i];
        }
        if (TB == 0) {
            const int j = tid & 63, kb = tid >> 6;
            #pragma unroll
            for (int rep = 0; rep < 4; rep++)
                Bs[kb + rep*4][j] = B[(long)(k0 + kb + rep*4)*ldb + j0 + j];
        } else if (TB == 1) {
            const int kk = tid & 15, jb = tid >> 4;
            #pragma unroll
            for (int rep = 0; rep < 4; rep++)
                Bs[kk][jb + rep*16] = B[(long)(j0 + jb + rep*16)*ldb + k0 + kk];
        } else {
            const int kk = tid & 15, jb = tid >> 4;
            const int kg = (k0 + kk) >> 6, kd = (k0 + kk) & 63;
            #pragma unroll
            for (int rep = 0; rep < 4; rep++)
                Bs[kk][jb + rep*16] = B[(long)kg*32768 + (long)(j0 + jb + rep*16)*64 + kd];
        }
        __syncthreads();
        #pragma unroll
        for (int kk = 0; kk < 16; kk++) {
            const float4 a4 = *(const float4*)&As[kk][tx*4];
            const float4 b4 = *(const float4*)&Bs[kk][ty*4];
            const float av[4] = {a4.x, a4.y, a4.z, a4.w};
            const float bv[4] = {b4.x, b4.y, b4.z, b4.w};
            #pragma unroll
            for (int ii = 0; ii < 4; ii++)
                #pragma unroll
                for (int jj = 0; jj < 4; jj++)
                    acc[ii][jj] = fmaf(av[ii], bv[jj], acc[ii][jj]);
        }
        __syncthreads();
    }

    #pragma unroll
    for (int ii = 0; ii < 4; ii++) {
        const int i = i0 + tx*4 + ii;
        const float sc = USE_SCALE ? (1.0f / srow[i]) : 1.0f;
        float4 v;
        v.x = acc[ii][0] * sc; v.y = acc[ii][1] * sc;
        v.z = acc[ii][2] * sc; v.w = acc[ii][3] * sc;
        *(float4*)(&C[(long)i*ldc + j0 + ty*4]) = v;
    }
}

// Single-problem GEMM (used for o-GEMM and final y-GEMM)
template<int TA, int TB, int USE_SCALE>
__global__ __launch_bounds__(256)
void gemm64(const float* __restrict__ Abase, const float* __restrict__ Bbase,
            float* __restrict__ Cbase, int lda, int ldb, int ldc, int Kdim,
            long sA_b, long sA_k, long sB_b, long sB_k, long sC_b, long sC_k,
            int ksplit, const float* __restrict__ scaleBase, long sScale)
{
    const int zb = blockIdx.z;
    const int b = zb / ksplit, k = zb % ksplit;
    gemm_body<TA, TB, USE_SCALE>(
        Abase + b*sA_b + k*sA_k, Bbase + b*sB_b + k*sB_k, Cbase + b*sC_b + k*sC_k,
        lda, ldb, ldc, Kdim, blockIdx.y*64, blockIdx.x*64,
        USE_SCALE ? (scaleBase + (long)zb*sScale) : nullptr);
}

// Triple-problem GEMM: 3 sub-GEMMs sharing lda/ldb/K, selected by blockIdx.z/16
struct G3 {
    const float* A[3]; const float* B[3]; float* C[3];
    int ldc[3]; int jt[3];
    long sAb[3], sAk[3], sBb[3], sBk[3], sCb[3], sCk[3];
};

template<int TA, int TB>
__global__ __launch_bounds__(256)
void gemm64m(G3 g, int lda, int ldb, int Kdim, int ksplit)
{
    const int zb = blockIdx.z;
    const int which = zb / (2*ksplit);
    const int sub = zb % (2*ksplit);
    const int b = sub / ksplit, k = sub % ksplit;
    if ((int)blockIdx.x >= g.jt[which]) return;
    gemm_body<TA, TB, 0>(
        g.A[which] + b*g.sAb[which] + k*g.sAk[which],
        g.B[which] + b*g.sBb[which] + k*g.sBk[which],
        g.C[which] + b*g.sCb[which] + k*g.sCk[which],
        lda, ldb, g.ldc[which], Kdim, blockIdx.y*64, blockIdx.x*64, nullptr);
}

// ---------------------------------------------------------------------------
// pass1: rbuf[b,k,m,n] += sum_r z[b,m,n,r] * wzy[b,k,m,r]
// block (m, b); z tile 64n x 128r staged in LDS with XOR-swizzled float4 cols.
// No cross-lane reductions: thread (k, nl) owns (n0+nl, n0+nl+32).
// ---------------------------------------------------------------------------
__global__ __launch_bounds__(256)
void pass1_kernel(const float* __restrict__ z, const float* __restrict__ wzy,
                  float* __restrict__ rbuf)
{
    const int m = blockIdx.x, b = blockIdx.y;
    __shared__ __align__(16) float zs[64*128];
    __shared__ __align__(16) float ws[8*128];
    const int tid = threadIdx.x;
    {
        const int k = tid >> 5, r4 = tid & 31;
        *(float4*)&ws[k*128 + r4*4] =
            *(const float4*)&wzy[(((long)b*8 + k)*256 + m)*128 + r4*4];
    }
    const int k = tid >> 5, nl = tid & 31;
    const int sw = nl & 7;
    __syncthreads();
    for (int n0 = 0; n0 < 256; n0 += 64) {
        if (n0) __syncthreads();
        const float4* zg = (const float4*)(z + (((long)b*256 + m)*256 + n0)*128);
        #pragma unroll
        for (int it = 0; it < 8; it++) {
            const int idx = it*256 + tid;
            const int nn = idx >> 5, r4 = idx & 31;
            ((float4*)zs)[nn*32 + (r4 ^ (nn & 7))] = zg[idx];
        }
        __syncthreads();
        float acc0 = 0.f, acc1 = 0.f;
        #pragma unroll 4
        for (int r4 = 0; r4 < 32; r4++) {
            const float4 wv = ((const float4*)ws)[k*32 + r4];
            const float4 z0 = ((const float4*)zs)[nl*32 + (r4 ^ sw)];
            const float4 z1 = ((const float4*)zs)[(nl + 32)*32 + (r4 ^ sw)];
            acc0 += z0.x*wv.x + z0.y*wv.y + z0.z*wv.z + z0.w*wv.w;
            acc1 += z1.x*wv.x + z1.y*wv.y + z1.z*wv.z + z1.w*wv.w;
        }
        float* rp = rbuf + (((long)b*8 + k)*256 + m)*256 + n0 + nl;
        rp[0]  += acc0;
        rp[32] += acc1;
    }
}

// ---------------------------------------------------------------------------
// pass2: rbufT[b,k,n,m] = sum_r z[b,m,n,r] * wzx[b,k,n,r]   (coalesced writes)
// block (n, b); symmetric to pass1 with m-tiles.
// ---------------------------------------------------------------------------
__global__ __launch_bounds__(256)
void pass2_kernel(const float* __restrict__ z, const float* __restrict__ wzx,
                  float* __restrict__ rbufT)
{
    const int n = blockIdx.x, b = blockIdx.y;
    __shared__ __align__(16) float zs[64*128];
    __shared__ __align__(16) float ws[8*128];
    const int tid = threadIdx.x;
    {
        const int k = tid >> 5, r4 = tid & 31;
        *(float4*)&ws[k*128 + r4*4] =
            *(const float4*)&wzx[(((long)b*8 + k)*256 + n)*128 + r4*4];
    }
    const int k = tid >> 5, ml = tid & 31;
    const int sw = ml & 7;
    __syncthreads();
    for (int m0 = 0; m0 < 256; m0 += 64) {
        if (m0) __syncthreads();
        #pragma unroll
        for (int it = 0; it < 8; it++) {
            const int idx = it*256 + tid;
            const int mm = idx >> 5, r4 = idx & 31;
            ((float4*)zs)[mm*32 + (r4 ^ (mm & 7))] =
                *(const float4*)(z + (((long)b*256 + m0 + mm)*256 + n)*128 + r4*4);
        }
        __syncthreads();
        float acc0 = 0.f, acc1 = 0.f;
        #pragma unroll 4
        for (int r4 = 0; r4 < 32; r4++) {
            const float4 wv = ((const float4*)ws)[k*32 + r4];
            const float4 z0 = ((const float4*)zs)[ml*32 + (r4 ^ sw)];
            const float4 z1 = ((const float4*)zs)[(ml + 32)*32 + (r4 ^ sw)];
            acc0 += z0.x*wv.x + z0.y*wv.y + z0.z*wv.z + z0.w*wv.w;
            acc1 += z1.x*wv.x + z1.y*wv.y + z1.z*wv.z + z1.w*wv.w;
        }
        float* rp = rbufT + (((long)b*8 + k)*256 + n)*256 + m0 + ml;
        rp[0]  = acc0;
        rp[32] = acc1;
    }
}

// ---------------------------------------------------------------------------
// softmax_combine: S = rbuf[bk,m,n-tile] (+) T = rbufT[bk,n-tile,m];
// e = exp((S+T)/TEMP) written to rbuf (unnormalized), column sums to ssum.
// No max-subtraction: |score|/TEMP << 88, fp32-safe; ratio identical to ref.
// block (bk, n-tile of 16), 256 threads.
// ---------------------------------------------------------------------------
__global__ __launch_bounds__(256)
void softmax_combine(const float* __restrict__ rbufT, float* __restrict__ rbuf,
                     float* __restrict__ ssum)
{
    const int bk = blockIdx.x;
    const int n0 = blockIdx.y * 16;
    const int tid = threadIdx.x;
    __shared__ float S[256][17];
    __shared__ __align__(16) float T[16][260];
    __shared__ float red[16][17];
    const float* rb = rbuf  + (long)bk * 65536;
    const float* rt = rbufT + (long)bk * 65536;
    {
        const int nn = tid & 15, mg = tid >> 4;
        #pragma unroll 4
        for (int i = 0; i < 16; i++) {
            const int m = mg*16 + i;
            S[m][nn] = rb[(long)m*256 + n0 + nn];
        }
    }
    {
        const int m4 = tid & 63, nq = tid >> 6;
        #pragma unroll
        for (int j = 0; j < 4; j++) {
            const int nn = nq*4 + j;
            *(float4*)&T[nn][m4*4] = *(const float4*)&rt[(long)(n0 + nn)*256 + m4*4];
        }
    }
    __syncthreads();
    const int nn = tid & 15, mg = tid >> 4;
    float loc = 0.f;
    float* outp = rbuf + (long)bk*65536 + n0 + nn;
    #pragma unroll 4
    for (int i = 0; i < 16; i++) {
        const int m = mg*16 + i;
        const float e = exp2f((S[m][nn] + T[nn][m]) * LOG2E_OVER_T);
        outp[(long)m*256] = e;
        loc += e;
    }
    red[mg][nn] = loc;
    __syncthreads();
    if (tid < 16) {
        float t = 0.f;
        #pragma unroll
        for (int g = 0; g < 16; g++) t += red[g][tid];
        ssum[bk*256 + n0 + tid] = t;
    }
}

// ---------------------------------------------------------------------------
extern "C" void kernel_launch(void* const* d_in, const int* in_sizes, int n_in,
                              void* d_out, int out_size, void* d_ws, size_t ws_size,
                              hipStream_t stream)
{
    const float* z       = (const float*)d_in[0];
    const float* y_q     = (const float*)d_in[1];
    const float* x_k     = (const float*)d_in[2];
    const float* Theta_x = (const float*)d_in[3];
    const float* Theta_y = (const float*)d_in[4];
    const float* Lam_x   = (const float*)d_in[5];
    const float* Lam_y   = (const float*)d_in[6];
    const float* Lam_zx  = (const float*)d_in[7];
    const float* Lam_zy  = (const float*)d_in[8];
    float* out = (float*)d_out;

    // Workspace layout (floats). rbufT aliases xt|yt|wzy (dead after pass1).
    float* ws    = (float*)d_ws;
    float* xt    = ws;                 // 262144  [B,K,256,64]
    float* yt    = ws + 262144;        // 262144  [B,K,256,64]
    float* wzy   = ws + 524288;        // 524288  [B,K,256,128]
    float* xv    = ws + 1048576;       // 262144  [B,K,256,64]
    float* wzx   = ws + 1310720;       // 524288  [B,K,256,128]
    float* rbuf  = ws + 1835008;       // 1048576 [B,K,256,256]
    float* ssum  = ws + 2883584;       // 4096    [B*K,256]
    float* o2    = ws + 2887680;       // 262144  [B,256,K*64]
    float* rbufT = ws;                 // 1048576 [B,K,256(n),256(m)] (alias)
    // total 3,149,824 floats = 12.6 MiB

    // 1. projections xt/yt/xv:  out[b,k,i,d] = sum_p in[b,i,p] * W[k,p,d]
    {
        G3 g;
        g.A[0] = x_k;   g.A[1] = y_q;   g.A[2] = x_k;
        g.B[0] = Lam_x; g.B[1] = Lam_y; g.B[2] = Theta_x;
        g.C[0] = xt;    g.C[1] = yt;    g.C[2] = xv;
        for (int i = 0; i < 3; i++) {
            g.ldc[i] = 64; g.jt[i] = 1;
            g.sAb[i] = 131072; g.sAk[i] = 0;
            g.sBb[i] = 0;      g.sBk[i] = 32768;
            g.sCb[i] = 131072; g.sCk[i] = 16384;
        }
        gemm64m<0,0><<<dim3(1,4,48), 256, 0, stream>>>(g, 512, 64, 512, 8);
    }

    // 2. wzy = xt @ Lam_zy^T, wzx = yt @ Lam_zx^T, rbuf = xt @ yt^T (xtyt init)
    {
        G3 g;
        g.A[0] = xt;     g.A[1] = yt;     g.A[2] = xt;
        g.B[0] = Lam_zy; g.B[1] = Lam_zx; g.B[2] = yt;
        g.C[0] = wzy;    g.C[1] = wzx;    g.C[2] = rbuf;
        g.ldc[0] = 128;  g.ldc[1] = 128;  g.ldc[2] = 256;
        g.jt[0] = 2;     g.jt[1] = 2;     g.jt[2] = 4;
        for (int i = 0; i < 3; i++) { g.sAb[i] = 131072; g.sAk[i] = 16384; }
        g.sBb[0] = 0;      g.sBb[1] = 0;      g.sBb[2] = 131072;
        g.sBk[0] = 8192;   g.sBk[1] = 8192;   g.sBk[2] = 16384;
        g.sCb[0] = 262144; g.sCb[1] = 262144; g.sCb[2] = 524288;
        g.sCk[0] = 32768;  g.sCk[1] = 32768;  g.sCk[2] = 65536;
        gemm64m<0,1><<<dim3(4,4,48), 256, 0, stream>>>(g, 64, 64, 64, 8);
    }

    // 3. rbuf += termB (z . wzy)
    pass1_kernel<<<dim3(256,2), 256, 0, stream>>>(z, wzy, rbuf);

    // 4. rbufT = termC (z . wzx), transposed layout  (overwrites xt/yt/wzy)
    pass2_kernel<<<dim3(256,2), 256, 0, stream>>>(z, wzx, rbufT);

    // 5. combine + exp + column sums;  rbuf := E (unnormalized)
    softmax_combine<<<dim3(16,16), 256, 0, stream>>>(rbufT, rbuf, ssum);

    // 6. o2[b,n,k*64+d] = (1/ssum[n]) * sum_m E[b,k,m,n] * xv[b,k,m,d]
    gemm64<1,0,1><<<dim3(1,4,16), 256, 0, stream>>>(rbuf, xv, o2,
        256, 64, 512, 256,
        524288L, 65536L, 131072L, 16384L, 131072L, 64L, 8, ssum, 256L);

    // 7. y[b,n,q] = sum_{k,d} o2[b,n,k*64+d] * Theta_y[k,q,d]   (TB=2 mode)
    gemm64<0,2,0><<<dim3(8,4,2), 256, 0, stream>>>(o2, Theta_y, out,
        512, 64, 512, 512,
        131072L, 0L, 0L, 0L, 131072L, 0L, 1, nullptr, 0L);
}

// Round 3
// 73.547 us; speedup vs baseline: 5.4274x; 1.7823x over previous
//
#include <hip/hip_runtime.h>
#include <hip/hip_bf16.h>

// B=2, M=256, N=256, K=8, P=Q=Pp=Qp=512, D=Dp=64, R=128, TEMP=8
#define LOG2E_OVER_T 0.18033688011112042f  // log2(e)/8

typedef __attribute__((ext_vector_type(8))) short short8;
typedef __attribute__((ext_vector_type(4))) float f32x4;
typedef unsigned short ushort_t;
typedef unsigned long long ull_t;

#define MFMA16(a, b, c) __builtin_amdgcn_mfma_f32_16x16x32_bf16(a, b, c, 0, 0, 0)

__device__ __forceinline__ ushort_t f2bf(float f) {
    union { float f; unsigned u; } v; v.f = f;
    unsigned r = (v.u + 0x7fffu + ((v.u >> 16) & 1u)) >> 16;
    return (ushort_t)r;
}

// ---------------------------------------------------------------------------
// MFMA core: C[64x64] = A[64xK] * Bt[64xK]^T, bf16 in, fp32 acc.
// 256 threads = 4 waves (2x2 quadrants), 2x2 16x16x32 frags per wave.
// LDS rows padded to 40 bf16 (80B) -> conflict-light ds_read_b128.
// Register prefetch of next K-tile hides global latency under MFMA.
// ---------------------------------------------------------------------------
__device__ __forceinline__ void mfma_core64(
    const ushort_t* __restrict__ Ag, int lda,
    const ushort_t* __restrict__ Btg, int ldb,
    int ksteps, f32x4 acc[2][2])
{
    __shared__ __align__(16) ushort_t As[64 * 40];
    __shared__ __align__(16) ushort_t Bs[64 * 40];
    const int t = threadIdx.x;
    const int srow = t >> 2, skc = (t & 3) * 8;
    const int lane = t & 63, w = t >> 6;
    const int wr = w >> 1, wc = w & 1;
    const int fr = lane & 15, kg = lane >> 4;
    const int aoff = (wr * 32 + fr) * 40 + kg * 8;
    const int boff = (wc * 32 + fr) * 40 + kg * 8;
    const long arow = (long)srow * lda + skc;
    const long brow = (long)srow * ldb + skc;

    short8 ra = *(const short8*)(Ag + arow);
    short8 rb = *(const short8*)(Btg + brow);
    for (int kt = 0; kt < ksteps; kt++) {
        __syncthreads();
        *(short8*)&As[srow * 40 + skc] = ra;
        *(short8*)&Bs[srow * 40 + skc] = rb;
        __syncthreads();
        if (kt + 1 < ksteps) {
            ra = *(const short8*)(Ag + arow + (kt + 1) * 32);
            rb = *(const short8*)(Btg + brow + (kt + 1) * 32);
        }
        short8 a0 = *(const short8*)&As[aoff];
        short8 a1 = *(const short8*)&As[aoff + 16 * 40];
        short8 b0 = *(const short8*)&Bs[boff];
        short8 b1 = *(const short8*)&Bs[boff + 16 * 40];
        acc[0][0] = MFMA16(a0, b0, acc[0][0]);
        acc[0][1] = MFMA16(a0, b1, acc[0][1]);
        acc[1][0] = MFMA16(a1, b0, acc[1][0]);
        acc[1][1] = MFMA16(a1, b1, acc[1][1]);
    }
}

__device__ __forceinline__ void zero_acc(f32x4 acc[2][2]) {
    const f32x4 z4 = {0.f, 0.f, 0.f, 0.f};
    acc[0][0] = z4; acc[0][1] = z4; acc[1][0] = z4; acc[1][1] = z4;
}

// ---------------------------------------------------------------------------
// convert: fp32 -> bf16 casts + layout permutes (all B^T-natural layouts)
// ---------------------------------------------------------------------------
__global__ __launch_bounds__(256)
void convert_kernel(const float* __restrict__ x_k, const float* __restrict__ y_q,
                    const float* __restrict__ Lam_x, const float* __restrict__ Theta_x,
                    const float* __restrict__ Lam_y, const float* __restrict__ Lam_zy,
                    const float* __restrict__ Lam_zx, const float* __restrict__ Theta_y,
                    ushort_t* __restrict__ xkb, ushort_t* __restrict__ yqb,
                    ushort_t* __restrict__ WxTb, ushort_t* __restrict__ WyTb,
                    ushort_t* __restrict__ Zyb, ushort_t* __restrict__ Zxb,
                    ushort_t* __restrict__ TyTb)
{
    int i = blockIdx.x * 256 + threadIdx.x;
    if (i < 262144) { xkb[i] = f2bf(x_k[i]); return; }
    i -= 262144;
    if (i < 262144) { yqb[i] = f2bf(y_q[i]); return; }
    i -= 262144;
    if (i < 524288) {  // WxTb[k][dc][p] = (dc<64 ? Lam_x : Theta_x)[k][p][dc%64]
        const int k = i >> 16, rem = i & 65535, dc = rem >> 9, p = i & 511;
        const float v = (dc < 64) ? Lam_x[((long)k * 512 + p) * 64 + dc]
                                  : Theta_x[((long)k * 512 + p) * 64 + dc - 64];
        WxTb[i] = f2bf(v); return;
    }
    i -= 524288;
    if (i < 262144) {  // WyTb[k][d][p] = Lam_y[k][p][d]
        const int k = i >> 15, d = (i >> 9) & 63, p = i & 511;
        WyTb[i] = f2bf(Lam_y[((long)k * 512 + p) * 64 + d]); return;
    }
    i -= 262144;
    if (i < 65536) { Zyb[i] = f2bf(Lam_zy[i]); return; }
    i -= 65536;
    if (i < 65536) { Zxb[i] = f2bf(Lam_zx[i]); return; }
    i -= 65536;
    {   // TyTb[q][k*64+d] = Theta_y[k][q][d]
        const int q = i >> 9, kd = i & 511, k = kd >> 6, d = kd & 63;
        TyTb[i] = f2bf(Theta_y[((long)k * 512 + q) * 64 + d]);
    }
}

// ---------------------------------------------------------------------------
// proj: side0: [b,m] x WxT -> xtb (bf16 [bk][m][64]) + xvT (bf16 [bk][64][m])
//       side1: [b,n] x WyT -> ytb (bf16 [bk][n][64])
// ---------------------------------------------------------------------------
__global__ __launch_bounds__(256)
void proj_kernel(const ushort_t* __restrict__ xkb, const ushort_t* __restrict__ yqb,
                 const ushort_t* __restrict__ WxTb, const ushort_t* __restrict__ WyTb,
                 ushort_t* __restrict__ xtb, ushort_t* __restrict__ ytb,
                 ushort_t* __restrict__ xvTb)
{
    const int side = blockIdx.z;
    const int bx = blockIdx.x, by = blockIdx.y;
    if (side == 1 && bx >= 8) return;
    f32x4 acc[2][2]; zero_acc(acc);
    const int t = threadIdx.x, lane = t & 63, w = t >> 6;
    const int wr = w >> 1, wc = w & 1, fr = lane & 15, kg = lane >> 4;

    if (side == 0) {
        mfma_core64(xkb + (long)(by * 64) * 512, 512,
                    WxTb + (long)(bx * 64) * 512, 512, 16, acc);
        const int k = bx >> 1, isxv = bx & 1;
        #pragma unroll
        for (int mi = 0; mi < 2; mi++)
        #pragma unroll
        for (int ni = 0; ni < 2; ni++) {
            const int grow0 = by * 64 + wr * 32 + mi * 16 + kg * 4;
            const int b = grow0 >> 8, m0 = grow0 & 255;
            const int d = wc * 32 + ni * 16 + fr;
            if (!isxv) {
                #pragma unroll
                for (int j = 0; j < 4; j++)
                    xtb[(((long)(b * 8 + k)) * 256 + m0 + j) * 64 + d] = f2bf(acc[mi][ni][j]);
            } else {
                ull_t pk = (ull_t)f2bf(acc[mi][ni][0])
                         | ((ull_t)f2bf(acc[mi][ni][1]) << 16)
                         | ((ull_t)f2bf(acc[mi][ni][2]) << 32)
                         | ((ull_t)f2bf(acc[mi][ni][3]) << 48);
                *(ull_t*)&xvTb[(((long)(b * 8 + k)) * 64 + d) * 256 + m0] = pk;
            }
        }
    } else {
        mfma_core64(yqb + (long)(by * 64) * 512, 512,
                    WyTb + (long)(bx * 64) * 512, 512, 16, acc);
        const int k = bx;
        #pragma unroll
        for (int mi = 0; mi < 2; mi++)
        #pragma unroll
        for (int ni = 0; ni < 2; ni++)
        #pragma unroll
        for (int j = 0; j < 4; j++) {
            const int grow = by * 64 + wr * 32 + mi * 16 + kg * 4 + j;
            const int b = grow >> 8, n = grow & 255;
            const int d = wc * 32 + ni * 16 + fr;
            ytb[(((long)(b * 8 + k)) * 256 + n) * 64 + d] = f2bf(acc[mi][ni][j]);
        }
    }
}

// ---------------------------------------------------------------------------
// step2 (fused, 512 blocks): wzy = xt@Lam_zy^T, wzx = yt@Lam_zx^T (fp32),
// rbuf = xt@yt^T (fp32 init of scores). All K=64.
// ---------------------------------------------------------------------------
__global__ __launch_bounds__(256)
void step2_kernel(const ushort_t* __restrict__ xtb, const ushort_t* __restrict__ ytb,
                  const ushort_t* __restrict__ Zyb, const ushort_t* __restrict__ Zxb,
                  float* __restrict__ wzy, float* __restrict__ wzx,
                  float* __restrict__ rbuf)
{
    const int bz = blockIdx.x;
    const ushort_t *Ag, *Btg;
    float* C; int ldc; long coff;
    if (bz < 256) {
        const int which = bz >> 7, idx = bz & 127;
        const int bk = idx >> 3, tile = idx & 7, mt = tile >> 1, nt = tile & 1;
        const int k = bk & 7;
        Ag = (which ? ytb : xtb) + ((long)bk * 256 + mt * 64) * 64;
        Btg = (which ? Zxb : Zyb) + ((long)k * 128 + nt * 64) * 64;
        C = which ? wzx : wzy; ldc = 128;
        coff = ((long)bk * 256 + mt * 64) * 128 + nt * 64;
    } else {
        const int idx = bz - 256;
        const int bk = idx >> 4, tile = idx & 15, mt = tile >> 2, nt = tile & 3;
        Ag = xtb + ((long)bk * 256 + mt * 64) * 64;
        Btg = ytb + ((long)bk * 256 + nt * 64) * 64;
        C = rbuf; ldc = 256;
        coff = ((long)bk * 256 + mt * 64) * 256 + nt * 64;
    }
    f32x4 acc[2][2]; zero_acc(acc);
    mfma_core64(Ag, 64, Btg, 64, 2, acc);
    const int t = threadIdx.x, lane = t & 63, w = t >> 6;
    const int wr = w >> 1, wc = w & 1, fr = lane & 15, kg = lane >> 4;
    #pragma unroll
    for (int mi = 0; mi < 2; mi++)
    #pragma unroll
    for (int ni = 0; ni < 2; ni++)
    #pragma unroll
    for (int j = 0; j < 4; j++)
        C[coff + (long)(wr * 32 + mi * 16 + kg * 4 + j) * ldc + wc * 32 + ni * 16 + fr]
            = acc[mi][ni][j];
}

// ---------------------------------------------------------------------------
// pass1: rbuf[b,k,m,n] += sum_r z[b,m,n,r] * wzy[b,k,m,r]   (fp32, unchanged)
// ---------------------------------------------------------------------------
__global__ __launch_bounds__(256)
void pass1_kernel(const float* __restrict__ z, const float* __restrict__ wzy,
                  float* __restrict__ rbuf)
{
    const int m = blockIdx.x, b = blockIdx.y;
    __shared__ __align__(16) float zs[64 * 128];
    __shared__ __align__(16) float ws[8 * 128];
    const int tid = threadIdx.x;
    {
        const int k = tid >> 5, r4 = tid & 31;
        *(float4*)&ws[k * 128 + r4 * 4] =
            *(const float4*)&wzy[(((long)b * 8 + k) * 256 + m) * 128 + r4 * 4];
    }
    const int k = tid >> 5, nl = tid & 31;
    const int sw = nl & 7;
    __syncthreads();
    for (int n0 = 0; n0 < 256; n0 += 64) {
        if (n0) __syncthreads();
        const float4* zg = (const float4*)(z + (((long)b * 256 + m) * 256 + n0) * 128);
        #pragma unroll
        for (int it = 0; it < 8; it++) {
            const int idx = it * 256 + tid;
            const int nn = idx >> 5, r4 = idx & 31;
            ((float4*)zs)[nn * 32 + (r4 ^ (nn & 7))] = zg[idx];
        }
        __syncthreads();
        float acc0 = 0.f, acc1 = 0.f;
        #pragma unroll 4
        for (int r4 = 0; r4 < 32; r4++) {
            const float4 wv = ((const float4*)ws)[k * 32 + r4];
            const float4 z0 = ((const float4*)zs)[nl * 32 + (r4 ^ sw)];
            const float4 z1 = ((const float4*)zs)[(nl + 32) * 32 + (r4 ^ sw)];
            acc0 += z0.x * wv.x + z0.y * wv.y + z0.z * wv.z + z0.w * wv.w;
            acc1 += z1.x * wv.x + z1.y * wv.y + z1.z * wv.z + z1.w * wv.w;
        }
        float* rp = rbuf + (((long)b * 8 + k) * 256 + m) * 256 + n0 + nl;
        rp[0]  += acc0;
        rp[32] += acc1;
    }
}

// ---------------------------------------------------------------------------
// pass2: rbufT[b,k,n,m] = sum_r z[b,m,n,r] * wzx[b,k,n,r]   (fp32, unchanged)
// ---------------------------------------------------------------------------
__global__ __launch_bounds__(256)
void pass2_kernel(const float* __restrict__ z, const float* __restrict__ wzx,
                  float* __restrict__ rbufT)
{
    const int n = blockIdx.x, b = blockIdx.y;
    __shared__ __align__(16) float zs[64 * 128];
    __shared__ __align__(16) float ws[8 * 128];
    const int tid = threadIdx.x;
    {
        const int k = tid >> 5, r4 = tid & 31;
        *(float4*)&ws[k * 128 + r4 * 4] =
            *(const float4*)&wzx[(((long)b * 8 + k) * 256 + n) * 128 + r4 * 4];
    }
    const int k = tid >> 5, ml = tid & 31;
    const int sw = ml & 7;
    __syncthreads();
    for (int m0 = 0; m0 < 256; m0 += 64) {
        if (m0) __syncthreads();
        #pragma unroll
        for (int it = 0; it < 8; it++) {
            const int idx = it * 256 + tid;
            const int mm = idx >> 5, r4 = idx & 31;
            ((float4*)zs)[mm * 32 + (r4 ^ (mm & 7))] =
                *(const float4*)(z + (((long)b * 256 + m0 + mm) * 256 + n) * 128 + r4 * 4);
        }
        __syncthreads();
        float acc0 = 0.f, acc1 = 0.f;
        #pragma unroll 4
        for (int r4 = 0; r4 < 32; r4++) {
            const float4 wv = ((const float4*)ws)[k * 32 + r4];
            const float4 z0 = ((const float4*)zs)[ml * 32 + (r4 ^ sw)];
            const float4 z1 = ((const float4*)zs)[(ml + 32) * 32 + (r4 ^ sw)];
            acc0 += z0.x * wv.x + z0.y * wv.y + z0.z * wv.z + z0.w * wv.w;
            acc1 += z1.x * wv.x + z1.y * wv.y + z1.z * wv.z + z1.w * wv.w;
        }
        float* rp = rbufT + (((long)b * 8 + k) * 256 + n) * 256 + m0 + ml;
        rp[0]  = acc0;
        rp[32] = acc1;
    }
}

// ---------------------------------------------------------------------------
// softmax_combine: e = exp((S+T)/TEMP); writes E^T bf16 [bk][n][m] + col sums.
// ---------------------------------------------------------------------------
__global__ __launch_bounds__(256)
void softmax_combine(const float* __restrict__ rbuf, const float* __restrict__ rbufT,
                     ushort_t* __restrict__ Et, float* __restrict__ ssum)
{
    const int bk = blockIdx.x;
    const int n0 = blockIdx.y * 16;
    const int tid = threadIdx.x;
    __shared__ float S[256][17];
    __shared__ __align__(16) float T[16][260];
    __shared__ float red[16][17];
    const float* rb = rbuf + (long)bk * 65536;
    const float* rt = rbufT + (long)bk * 65536;
    {
        const int nn = tid & 15, mg = tid >> 4;
        #pragma unroll 4
        for (int i = 0; i < 16; i++) {
            const int m = mg * 16 + i;
            S[m][nn] = rb[(long)m * 256 + n0 + nn];
        }
    }
    {
        const int m4 = tid & 63, nq = tid >> 6;
        #pragma unroll
        for (int j = 0; j < 4; j++) {
            const int nn = nq * 4 + j;
            *(float4*)&T[nn][m4 * 4] = *(const float4*)&rt[(long)(n0 + nn) * 256 + m4 * 4];
        }
    }
    __syncthreads();
    const int nn = tid & 15, mg = tid >> 4;
    float loc = 0.f;
    ushort_t ebuf[16];
    #pragma unroll
    for (int i = 0; i < 16; i++) {
        const int m = mg * 16 + i;
        const float e = exp2f((S[m][nn] + T[nn][m]) * LOG2E_OVER_T);
        ebuf[i] = f2bf(e);
        loc += e;
    }
    ushort_t* ep = Et + ((long)bk * 256 + n0 + nn) * 256 + mg * 16;
    *(short8*)(ep)     = *(short8*)&ebuf[0];
    *(short8*)(ep + 8) = *(short8*)&ebuf[8];
    red[mg][nn] = loc;
    __syncthreads();
    if (tid < 16) {
        float s2 = 0.f;
        #pragma unroll
        for (int g = 0; g < 16; g++) s2 += red[g][tid];
        ssum[bk * 256 + n0 + tid] = s2;
    }
}

// ---------------------------------------------------------------------------
// ogemm: o2b[b][n][k*64+d] = bf16( (1/ssum[bk][n]) * sum_m Et[bk][n][m]*xvT[bk][d][m] )
// ---------------------------------------------------------------------------
__global__ __launch_bounds__(256)
void ogemm_kernel(const ushort_t* __restrict__ Et, const ushort_t* __restrict__ xvTb,
                  const float* __restrict__ ssum, ushort_t* __restrict__ o2b)
{
    const int mt = blockIdx.x, bk = blockIdx.y;
    f32x4 acc[2][2]; zero_acc(acc);
    mfma_core64(Et + ((long)bk * 256 + mt * 64) * 256, 256,
                xvTb + (long)bk * 64 * 256, 256, 8, acc);
    const int t = threadIdx.x, lane = t & 63, w = t >> 6;
    const int wr = w >> 1, wc = w & 1, fr = lane & 15, kg = lane >> 4;
    const int b = bk >> 3, k = bk & 7;
    #pragma unroll
    for (int mi = 0; mi < 2; mi++)
    #pragma unroll
    for (int j = 0; j < 4; j++) {
        const int n = mt * 64 + wr * 32 + mi * 16 + kg * 4 + j;
        const float inv = 1.0f / ssum[bk * 256 + n];
        #pragma unroll
        for (int ni = 0; ni < 2; ni++) {
            const int d = wc * 32 + ni * 16 + fr;
            o2b[((long)b * 256 + n) * 512 + k * 64 + d] = f2bf(acc[mi][ni][j] * inv);
        }
    }
}

// ---------------------------------------------------------------------------
// ygemm: out[b][n][q] = sum_kd o2b[b][n][kd] * TyTb[q][kd]   (fp32 out)
// ---------------------------------------------------------------------------
__global__ __launch_bounds__(256)
void ygemm_kernel(const ushort_t* __restrict__ o2b, const ushort_t* __restrict__ TyTb,
                  float* __restrict__ out)
{
    const int qt = blockIdx.x, mt = blockIdx.y, b = blockIdx.z;
    f32x4 acc[2][2]; zero_acc(acc);
    mfma_core64(o2b + ((long)b * 256 + mt * 64) * 512, 512,
                TyTb + (long)qt * 64 * 512, 512, 16, acc);
    const int t = threadIdx.x, lane = t & 63, w = t >> 6;
    const int wr = w >> 1, wc = w & 1, fr = lane & 15, kg = lane >> 4;
    #pragma unroll
    for (int mi = 0; mi < 2; mi++)
    #pragma unroll
    for (int ni = 0; ni < 2; ni++)
    #pragma unroll
    for (int j = 0; j < 4; j++) {
        const int n = mt * 64 + wr * 32 + mi * 16 + kg * 4 + j;
        const int q = qt * 64 + wc * 32 + ni * 16 + fr;
        out[((long)b * 256 + n) * 512 + q] = acc[mi][ni][j];
    }
}

// ---------------------------------------------------------------------------
extern "C" void kernel_launch(void* const* d_in, const int* in_sizes, int n_in,
                              void* d_out, int out_size, void* d_ws, size_t ws_size,
                              hipStream_t stream)
{
    const float* z       = (const float*)d_in[0];
    const float* y_q     = (const float*)d_in[1];
    const float* x_k     = (const float*)d_in[2];
    const float* Theta_x = (const float*)d_in[3];
    const float* Theta_y = (const float*)d_in[4];
    const float* Lam_x   = (const float*)d_in[5];
    const float* Lam_y   = (const float*)d_in[6];
    const float* Lam_zx  = (const float*)d_in[7];
    const float* Lam_zy  = (const float*)d_in[8];
    float* out = (float*)d_out;

    // --- workspace layout (14 MiB high-water, phase-aliased) ---
    float*    ws   = (float*)d_ws;
    ushort_t* U    = (ushort_t*)d_ws;
    // [0, 4MB): rbufT (pass2 output) ALIASES the convert-phase tensors below
    float*    rbufT = ws;
    ushort_t* WxTb  = U;               // 1MB   [8*128][512]
    ushort_t* WyTb  = U + 524288;      // 0.5MB [8*64][512]
    ushort_t* Zyb   = U + 786432;      // 128KB [8][128][64]
    ushort_t* Zxb   = U + 851968;      // 128KB
    ushort_t* xkb   = U + 917504;      // 0.5MB [512][512]
    ushort_t* yqb   = U + 1179648;     // 0.5MB
    // [4MB, 8MB): rbuf fp32 scores/E
    float*    rbuf  = ws + 1048576;
    // [8MB, 10MB): wzy fp32 ; later Et bf16 [16][256][256]
    float*    wzy   = ws + 2097152;
    ushort_t* Et    = U + 4194304;
    // [10MB, 12MB): wzx fp32
    float*    wzx   = ws + 2621440;
    // [12MB, 14MB): bf16 tensors
    ushort_t* xtb   = U + 6291456;     // 0.5MB [16][256][64]; later o2b alias
    ushort_t* o2b   = xtb;
    ushort_t* ytb   = U + 6553600;     // 0.5MB; later ssum alias
    float*    ssum  = ws + 3276800;    // 16KB  [16][256]
    ushort_t* xvTb  = U + 6815744;     // 0.5MB [16][64][256]
    ushort_t* TyTb  = U + 7077888;     // 0.5MB [512][512]

    convert_kernel<<<6656, 256, 0, stream>>>(x_k, y_q, Lam_x, Theta_x, Lam_y,
        Lam_zy, Lam_zx, Theta_y, xkb, yqb, WxTb, WyTb, Zyb, Zxb, TyTb);

    proj_kernel<<<dim3(16, 8, 2), 256, 0, stream>>>(xkb, yqb, WxTb, WyTb,
        xtb, ytb, xvTb);

    step2_kernel<<<512, 256, 0, stream>>>(xtb, ytb, Zyb, Zxb, wzy, wzx, rbuf);

    pass1_kernel<<<dim3(256, 2), 256, 0, stream>>>(z, wzy, rbuf);

    pass2_kernel<<<dim3(256, 2), 256, 0, stream>>>(z, wzx, rbufT);

    softmax_combine<<<dim3(16, 16), 256, 0, stream>>>(rbuf, rbufT, Et, ssum);

    ogemm_kernel<<<dim3(4, 16), 256, 0, stream>>>(Et, xvTb, ssum, o2b);

    ygemm_kernel<<<dim3(8, 4, 2), 256, 0, stream>>>(o2b, TyTb, out);
}

// Round 4
// 71.048 us; speedup vs baseline: 5.6183x; 1.0352x over previous
//
#include <hip/hip_runtime.h>
#include <hip/hip_bf16.h>

// B=2, M=256, N=256, K=8, P=Q=Pp=Qp=512, D=Dp=64, R=128, TEMP=8
#define LOG2E_OVER_T 0.18033688011112042f  // log2(e)/8

typedef __attribute__((ext_vector_type(8))) short short8;
typedef __attribute__((ext_vector_type(4))) float f32x4;
typedef unsigned short ushort_t;
typedef unsigned long long ull_t;

#define MFMA16(a, b, c) __builtin_amdgcn_mfma_f32_16x16x32_bf16(a, b, c, 0, 0, 0)

__device__ __forceinline__ ushort_t f2bf(float f) {
    union { float f; unsigned u; } v; v.f = f;
    unsigned r = (v.u + 0x7fffu + ((v.u >> 16) & 1u)) >> 16;
    return (ushort_t)r;
}

// split 8 fp32 -> bf16 hi (truncate) + bf16 lo (residual, truncate).
// hi+lo reconstructs z to ~2^-16 relative: fp32-grade z through 2 MFMAs.
__device__ __forceinline__ void split8(const float4 a, const float4 b,
                                       short8& hi, short8& lo)
{
    union { float f[8]; unsigned u[8]; } Z;
    Z.f[0] = a.x; Z.f[1] = a.y; Z.f[2] = a.z; Z.f[3] = a.w;
    Z.f[4] = b.x; Z.f[5] = b.y; Z.f[6] = b.z; Z.f[7] = b.w;
    union { unsigned u[4]; short8 s; } H, L;
    #pragma unroll
    for (int i = 0; i < 4; i++) {
        const unsigned u0 = Z.u[2 * i], u1 = Z.u[2 * i + 1];
        H.u[i] = __builtin_amdgcn_perm(u1, u0, 0x07060302u);  // [u0.hi16, u1.hi16]
        union { unsigned u; float f; } h0, h1;
        h0.u = u0 & 0xffff0000u; h1.u = u1 & 0xffff0000u;
        union { float f; unsigned u; } l0, l1;
        l0.f = Z.f[2 * i] - h0.f; l1.f = Z.f[2 * i + 1] - h1.f;
        L.u[i] = __builtin_amdgcn_perm(l1.u, l0.u, 0x07060302u);
    }
    hi = H.s; lo = L.s;
}

// ---------------------------------------------------------------------------
// MFMA core: C[64x64] = A[64xK] * Bt[64xK]^T, bf16 in, fp32 acc.
// 256 threads = 4 waves (2x2 quadrants), 2x2 16x16x32 frags per wave.
// ---------------------------------------------------------------------------
__device__ __forceinline__ void mfma_core64(
    const ushort_t* __restrict__ Ag, int lda,
    const ushort_t* __restrict__ Btg, int ldb,
    int ksteps, f32x4 acc[2][2])
{
    __shared__ __align__(16) ushort_t As[64 * 40];
    __shared__ __align__(16) ushort_t Bs[64 * 40];
    const int t = threadIdx.x;
    const int srow = t >> 2, skc = (t & 3) * 8;
    const int lane = t & 63, w = t >> 6;
    const int wr = w >> 1, wc = w & 1;
    const int fr = lane & 15, kg = lane >> 4;
    const int aoff = (wr * 32 + fr) * 40 + kg * 8;
    const int boff = (wc * 32 + fr) * 40 + kg * 8;
    const long arow = (long)srow * lda + skc;
    const long brow = (long)srow * ldb + skc;

    short8 ra = *(const short8*)(Ag + arow);
    short8 rb = *(const short8*)(Btg + brow);
    for (int kt = 0; kt < ksteps; kt++) {
        __syncthreads();
        *(short8*)&As[srow * 40 + skc] = ra;
        *(short8*)&Bs[srow * 40 + skc] = rb;
        __syncthreads();
        if (kt + 1 < ksteps) {
            ra = *(const short8*)(Ag + arow + (kt + 1) * 32);
            rb = *(const short8*)(Btg + brow + (kt + 1) * 32);
        }
        short8 a0 = *(const short8*)&As[aoff];
        short8 a1 = *(const short8*)&As[aoff + 16 * 40];
        short8 b0 = *(const short8*)&Bs[boff];
        short8 b1 = *(const short8*)&Bs[boff + 16 * 40];
        acc[0][0] = MFMA16(a0, b0, acc[0][0]);
        acc[0][1] = MFMA16(a0, b1, acc[0][1]);
        acc[1][0] = MFMA16(a1, b0, acc[1][0]);
        acc[1][1] = MFMA16(a1, b1, acc[1][1]);
    }
}

__device__ __forceinline__ void zero_acc(f32x4 acc[2][2]) {
    const f32x4 z4 = {0.f, 0.f, 0.f, 0.f};
    acc[0][0] = z4; acc[0][1] = z4; acc[1][0] = z4; acc[1][1] = z4;
}

// ---------------------------------------------------------------------------
// convert: fp32 -> bf16 casts + layout permutes; also zeroes ssum.
// ---------------------------------------------------------------------------
__global__ __launch_bounds__(256)
void convert_kernel(const float* __restrict__ x_k, const float* __restrict__ y_q,
                    const float* __restrict__ Lam_x, const float* __restrict__ Theta_x,
                    const float* __restrict__ Lam_y, const float* __restrict__ Lam_zy,
                    const float* __restrict__ Lam_zx, const float* __restrict__ Theta_y,
                    ushort_t* __restrict__ xkb, ushort_t* __restrict__ yqb,
                    ushort_t* __restrict__ WxTb, ushort_t* __restrict__ WyTb,
                    ushort_t* __restrict__ Zyb, ushort_t* __restrict__ Zxb,
                    ushort_t* __restrict__ TyTb, float* __restrict__ ssum)
{
    int i = blockIdx.x * 256 + threadIdx.x;
    if (i < 262144) { xkb[i] = f2bf(x_k[i]); return; }
    i -= 262144;
    if (i < 262144) { yqb[i] = f2bf(y_q[i]); return; }
    i -= 262144;
    if (i < 524288) {  // WxTb[k][dc][p] = (dc<64 ? Lam_x : Theta_x)[k][p][dc%64]
        const int k = i >> 16, rem = i & 65535, dc = rem >> 9, p = i & 511;
        const float v = (dc < 64) ? Lam_x[((long)k * 512 + p) * 64 + dc]
                                  : Theta_x[((long)k * 512 + p) * 64 + dc - 64];
        WxTb[i] = f2bf(v); return;
    }
    i -= 524288;
    if (i < 262144) {  // WyTb[k][d][p] = Lam_y[k][p][d]
        const int k = i >> 15, d = (i >> 9) & 63, p = i & 511;
        WyTb[i] = f2bf(Lam_y[((long)k * 512 + p) * 64 + d]); return;
    }
    i -= 262144;
    if (i < 65536) { Zyb[i] = f2bf(Lam_zy[i]); return; }
    i -= 65536;
    if (i < 65536) { Zxb[i] = f2bf(Lam_zx[i]); return; }
    i -= 65536;
    if (i < 262144) {  // TyTb[q][k*64+d] = Theta_y[k][q][d]
        const int q = i >> 9, kd = i & 511, k = kd >> 6, d = kd & 63;
        TyTb[i] = f2bf(Theta_y[((long)k * 512 + q) * 64 + d]); return;
    }
    i -= 262144;
    ssum[i] = 0.f;  // 4096 entries
}

// ---------------------------------------------------------------------------
// proj: side0: [b,m] x WxT -> xtb (bf16 [bk][m][64]) + xvT (bf16 [bk][64][m])
//       side1: [b,n] x WyT -> ytb (bf16 [bk][n][64])
// ---------------------------------------------------------------------------
__global__ __launch_bounds__(256)
void proj_kernel(const ushort_t* __restrict__ xkb, const ushort_t* __restrict__ yqb,
                 const ushort_t* __restrict__ WxTb, const ushort_t* __restrict__ WyTb,
                 ushort_t* __restrict__ xtb, ushort_t* __restrict__ ytb,
                 ushort_t* __restrict__ xvTb)
{
    const int side = blockIdx.z;
    const int bx = blockIdx.x, by = blockIdx.y;
    if (side == 1 && bx >= 8) return;
    f32x4 acc[2][2]; zero_acc(acc);
    const int t = threadIdx.x, lane = t & 63, w = t >> 6;
    const int wr = w >> 1, wc = w & 1, fr = lane & 15, kg = lane >> 4;

    if (side == 0) {
        mfma_core64(xkb + (long)(by * 64) * 512, 512,
                    WxTb + (long)(bx * 64) * 512, 512, 16, acc);
        const int k = bx >> 1, isxv = bx & 1;
        #pragma unroll
        for (int mi = 0; mi < 2; mi++)
        #pragma unroll
        for (int ni = 0; ni < 2; ni++) {
            const int grow0 = by * 64 + wr * 32 + mi * 16 + kg * 4;
            const int b = grow0 >> 8, m0 = grow0 & 255;
            const int d = wc * 32 + ni * 16 + fr;
            if (!isxv) {
                #pragma unroll
                for (int j = 0; j < 4; j++)
                    xtb[(((long)(b * 8 + k)) * 256 + m0 + j) * 64 + d] = f2bf(acc[mi][ni][j]);
            } else {
                ull_t pk = (ull_t)f2bf(acc[mi][ni][0])
                         | ((ull_t)f2bf(acc[mi][ni][1]) << 16)
                         | ((ull_t)f2bf(acc[mi][ni][2]) << 32)
                         | ((ull_t)f2bf(acc[mi][ni][3]) << 48);
                *(ull_t*)&xvTb[(((long)(b * 8 + k)) * 64 + d) * 256 + m0] = pk;
            }
        }
    } else {
        mfma_core64(yqb + (long)(by * 64) * 512, 512,
                    WyTb + (long)(bx * 64) * 512, 512, 16, acc);
        const int k = bx;
        #pragma unroll
        for (int mi = 0; mi < 2; mi++)
        #pragma unroll
        for (int ni = 0; ni < 2; ni++)
        #pragma unroll
        for (int j = 0; j < 4; j++) {
            const int grow = by * 64 + wr * 32 + mi * 16 + kg * 4 + j;
            const int b = grow >> 8, n = grow & 255;
            const int d = wc * 32 + ni * 16 + fr;
            ytb[(((long)(b * 8 + k)) * 256 + n) * 64 + d] = f2bf(acc[mi][ni][j]);
        }
    }
}

// ---------------------------------------------------------------------------
// step2: wzyb = bf16(xt @ Lam_zy^T), wzxb = bf16(yt @ Lam_zx^T)   [bk][m][128]
// ---------------------------------------------------------------------------
__global__ __launch_bounds__(256)
void step2_kernel(const ushort_t* __restrict__ xtb, const ushort_t* __restrict__ ytb,
                  const ushort_t* __restrict__ Zyb, const ushort_t* __restrict__ Zxb,
                  ushort_t* __restrict__ wzyb, ushort_t* __restrict__ wzxb)
{
    const int bz = blockIdx.x;  // 256
    const int which = bz >> 7, idx = bz & 127;
    const int bk = idx >> 3, tile = idx & 7, mt = tile >> 1, nt = tile & 1;
    const int k = bk & 7;
    const ushort_t* Ag  = (which ? ytb : xtb) + ((long)bk * 256 + mt * 64) * 64;
    const ushort_t* Btg = (which ? Zxb : Zyb) + ((long)k * 128 + nt * 64) * 64;
    ushort_t* C = which ? wzxb : wzyb;
    const long coff = ((long)bk * 256 + mt * 64) * 128 + nt * 64;
    f32x4 acc[2][2]; zero_acc(acc);
    mfma_core64(Ag, 64, Btg, 64, 2, acc);
    const int t = threadIdx.x, lane = t & 63, w = t >> 6;
    const int wr = w >> 1, wc = w & 1, fr = lane & 15, kg = lane >> 4;
    #pragma unroll
    for (int mi = 0; mi < 2; mi++)
    #pragma unroll
    for (int ni = 0; ni < 2; ni++)
    #pragma unroll
    for (int j = 0; j < 4; j++)
        C[coff + (long)(wr * 32 + mi * 16 + kg * 4 + j) * 128 + wc * 32 + ni * 16 + fr]
            = f2bf(acc[mi][ni][j]);
}

// ---------------------------------------------------------------------------
// fused_score: per block (b, 8m x 16n): score = xt.yt + z.wzy + z.wzx (MFMA,
// z split hi/lo in-register for fp32-grade precision), then exp -> Et bf16
// [bk][n][m] + atomicAdd column sums. z read from HBM exactly once.
// ---------------------------------------------------------------------------
__global__ __launch_bounds__(256, 4)
void fused_score(const float* __restrict__ z,
                 const ushort_t* __restrict__ xtb, const ushort_t* __restrict__ ytb,
                 const ushort_t* __restrict__ wzyb, const ushort_t* __restrict__ wzxb,
                 ushort_t* __restrict__ Et, float* __restrict__ ssum)
{
    const int nt = blockIdx.x, mt = blockIdx.y, b = blockIdx.z;
    const int m0 = mt * 8, n0 = nt * 16;
    __shared__ float sc[8 * 8 * 17];  // [k][m][n pad 17]
    const int t = threadIdx.x, lane = t & 63, w = t >> 6;
    const int fr = lane & 15, kg = lane >> 4;
    const int f8 = fr & 7;

    // ---- phase 1: xtyt.  A = yt rows n(16), B = xt rows m(8; dup fr>=8).
    // D[row=n=kg*4+j, col=m=fr]
    {
        const long ybase = ((long)(b * 8) * 256 + n0 + fr) * 64 + kg * 8;
        const long xbase = ((long)(b * 8) * 256 + m0 + f8) * 64 + kg * 8;
        #pragma unroll
        for (int kk = 0; kk < 2; kk++) {
            const int k = w * 2 + kk;
            const long ko = (long)k * 256 * 64;
            f32x4 acc = {0.f, 0.f, 0.f, 0.f};
            #pragma unroll
            for (int s = 0; s < 2; s++) {
                short8 av = *(const short8*)(ytb + ybase + ko + s * 32);
                short8 bv = *(const short8*)(xtb + xbase + ko + s * 32);
                acc = MFMA16(av, bv, acc);
            }
            if (fr < 8) {
                #pragma unroll
                for (int j = 0; j < 4; j++)
                    sc[k * 136 + fr * 17 + kg * 4 + j] = acc[j];
            }
        }
    }
    __syncthreads();

    // ---- phase 2: termB. per m: A = z[m] rows n(16), B = wzy[m] rows k.
    // D[row=n=kg*4+j, col=k=fr<8]
    {
        #pragma unroll
        for (int mi = 0; mi < 2; mi++) {
            const int ml = w * 2 + mi;
            const int m = m0 + ml;
            const float* zr = z + (((long)b * 256 + m) * 256 + n0 + fr) * 128 + kg * 8;
            const ushort_t* wp = wzyb + (((long)b * 8 + f8) * 256 + m) * 128 + kg * 8;
            f32x4 acc = {0.f, 0.f, 0.f, 0.f};
            #pragma unroll
            for (int s = 0; s < 4; s++) {
                float4 z0 = *(const float4*)(zr + s * 32);
                float4 z1 = *(const float4*)(zr + s * 32 + 4);
                short8 wv = *(const short8*)(wp + s * 32);
                short8 hi, lo;
                split8(z0, z1, hi, lo);
                acc = MFMA16(hi, wv, acc);
                acc = MFMA16(lo, wv, acc);
            }
            if (fr < 8) {
                #pragma unroll
                for (int j = 0; j < 4; j++)
                    sc[fr * 136 + ml * 17 + kg * 4 + j] += acc[j];
            }
        }
    }
    __syncthreads();

    // ---- phase 3: termC. per n: A = z[:,n] rows m(8; dup), B = wzx[n] rows k.
    // D[row=m=kg*4+j (valid<8), col=k=fr<8]
    {
        #pragma unroll
        for (int ni = 0; ni < 4; ni++) {
            const int nl = w * 4 + ni;
            const int n = n0 + nl;
            const float* zr = z + (((long)b * 256 + m0 + f8) * 256 + n) * 128 + kg * 8;
            const ushort_t* wp = wzxb + (((long)b * 8 + f8) * 256 + n) * 128 + kg * 8;
            f32x4 acc = {0.f, 0.f, 0.f, 0.f};
            #pragma unroll
            for (int s = 0; s < 4; s++) {
                float4 z0 = *(const float4*)(zr + s * 32);
                float4 z1 = *(const float4*)(zr + s * 32 + 4);
                short8 wv = *(const short8*)(wp + s * 32);
                short8 hi, lo;
                split8(z0, z1, hi, lo);
                acc = MFMA16(hi, wv, acc);
                acc = MFMA16(lo, wv, acc);
            }
            if (fr < 8 && kg < 2) {
                #pragma unroll
                for (int j = 0; j < 4; j++)
                    sc[fr * 136 + (kg * 4 + j) * 17 + nl] += acc[j];
            }
        }
    }
    __syncthreads();

    // ---- epilogue: exp -> Et bf16 + column-sum atomics
    if (t < 128) {
        const int k = t >> 4, nl = t & 15;
        float sum = 0.f;
        ushort_t eb[8];
        #pragma unroll
        for (int j = 0; j < 8; j++) {
            const float e = exp2f(sc[k * 136 + j * 17 + nl] * LOG2E_OVER_T);
            eb[j] = f2bf(e);
            sum += e;
        }
        *(short8*)(Et + (((long)b * 8 + k) * 256 + n0 + nl) * 256 + m0) = *(short8*)eb;
        atomicAdd(&ssum[(b * 8 + k) * 256 + n0 + nl], sum);
    }
}

// ---------------------------------------------------------------------------
// ogemm: o2b[b][n][k*64+d] = bf16( (1/ssum[bk][n]) * sum_m Et[bk][n][m]*xvT[bk][d][m] )
// ---------------------------------------------------------------------------
__global__ __launch_bounds__(256)
void ogemm_kernel(const ushort_t* __restrict__ Et, const ushort_t* __restrict__ xvTb,
                  const float* __restrict__ ssum, ushort_t* __restrict__ o2b)
{
    const int mt = blockIdx.x, bk = blockIdx.y;
    f32x4 acc[2][2]; zero_acc(acc);
    mfma_core64(Et + ((long)bk * 256 + mt * 64) * 256, 256,
                xvTb + (long)bk * 64 * 256, 256, 8, acc);
    const int t = threadIdx.x, lane = t & 63, w = t >> 6;
    const int wr = w >> 1, wc = w & 1, fr = lane & 15, kg = lane >> 4;
    const int b = bk >> 3, k = bk & 7;
    #pragma unroll
    for (int mi = 0; mi < 2; mi++)
    #pragma unroll
    for (int j = 0; j < 4; j++) {
        const int n = mt * 64 + wr * 32 + mi * 16 + kg * 4 + j;
        const float inv = 1.0f / ssum[bk * 256 + n];
        #pragma unroll
        for (int ni = 0; ni < 2; ni++) {
            const int d = wc * 32 + ni * 16 + fr;
            o2b[((long)b * 256 + n) * 512 + k * 64 + d] = f2bf(acc[mi][ni][j] * inv);
        }
    }
}

// ---------------------------------------------------------------------------
// ygemm: out[b][n][q] = sum_kd o2b[b][n][kd] * TyTb[q][kd]   (fp32 out)
// ---------------------------------------------------------------------------
__global__ __launch_bounds__(256)
void ygemm_kernel(const ushort_t* __restrict__ o2b, const ushort_t* __restrict__ TyTb,
                  float* __restrict__ out)
{
    const int qt = blockIdx.x, mt = blockIdx.y, b = blockIdx.z;
    f32x4 acc[2][2]; zero_acc(acc);
    mfma_core64(o2b + ((long)b * 256 + mt * 64) * 512, 512,
                TyTb + (long)qt * 64 * 512, 512, 16, acc);
    const int t = threadIdx.x, lane = t & 63, w = t >> 6;
    const int wr = w >> 1, wc = w & 1, fr = lane & 15, kg = lane >> 4;
    #pragma unroll
    for (int mi = 0; mi < 2; mi++)
    #pragma unroll
    for (int ni = 0; ni < 2; ni++)
    #pragma unroll
    for (int j = 0; j < 4; j++) {
        const int n = mt * 64 + wr * 32 + mi * 16 + kg * 4 + j;
        const int q = qt * 64 + wc * 32 + ni * 16 + fr;
        out[((long)b * 256 + n) * 512 + q] = acc[mi][ni][j];
    }
}

// ---------------------------------------------------------------------------
extern "C" void kernel_launch(void* const* d_in, const int* in_sizes, int n_in,
                              void* d_out, int out_size, void* d_ws, size_t ws_size,
                              hipStream_t stream)
{
    const float* z       = (const float*)d_in[0];
    const float* y_q     = (const float*)d_in[1];
    const float* x_k     = (const float*)d_in[2];
    const float* Theta_x = (const float*)d_in[3];
    const float* Theta_y = (const float*)d_in[4];
    const float* Lam_x   = (const float*)d_in[5];
    const float* Lam_y   = (const float*)d_in[6];
    const float* Lam_zx  = (const float*)d_in[7];
    const float* Lam_zy  = (const float*)d_in[8];
    float* out = (float*)d_out;

    // --- workspace (ushort offsets, all disjoint, ~9.7 MiB total) ---
    ushort_t* U = (ushort_t*)d_ws;
    ushort_t* xkb  = U;               // 262144  [b][m][512]
    ushort_t* yqb  = U + 262144;      // 262144  [b][n][512]
    ushort_t* WxTb = U + 524288;      // 524288  [k][128dc][512p]
    ushort_t* WyTb = U + 1048576;     // 262144  [k][64d][512p]
    ushort_t* Zyb  = U + 1310720;     // 65536   [k][128r][64d]
    ushort_t* Zxb  = U + 1376256;     // 65536
    ushort_t* TyTb = U + 1441792;     // 262144  [q][k*64+d]
    ushort_t* xtb  = U + 1703936;     // 262144  [bk][m][64]
    ushort_t* ytb  = U + 1966080;     // 262144  [bk][n][64]
    ushort_t* xvTb = U + 2228224;     // 262144  [bk][64d][256m]
    ushort_t* wzyb = U + 2490368;     // 524288  [bk][m][128r]
    ushort_t* wzxb = U + 3014656;     // 524288  [bk][n][128r]
    ushort_t* Et   = U + 3538944;     // 1048576 [bk][n][256m]
    ushort_t* o2b  = U + 4587520;     // 262144  [b][n][512kd]
    float*    ssum = (float*)(U + 4849664);  // 4096 fp32 [bk][n]

    convert_kernel<<<6672, 256, 0, stream>>>(x_k, y_q, Lam_x, Theta_x, Lam_y,
        Lam_zy, Lam_zx, Theta_y, xkb, yqb, WxTb, WyTb, Zyb, Zxb, TyTb, ssum);

    proj_kernel<<<dim3(16, 8, 2), 256, 0, stream>>>(xkb, yqb, WxTb, WyTb,
        xtb, ytb, xvTb);

    step2_kernel<<<256, 256, 0, stream>>>(xtb, ytb, Zyb, Zxb, wzyb, wzxb);

    fused_score<<<dim3(16, 32, 2), 256, 0, stream>>>(z, xtb, ytb, wzyb, wzxb,
        Et, ssum);

    ogemm_kernel<<<dim3(4, 16), 256, 0, stream>>>(Et, xvTb, ssum, o2b);

    ygemm_kernel<<<dim3(8, 4, 2), 256, 0, stream>>>(o2b, TyTb, out);
}